// Round 5
// baseline (672.823 us; speedup 1.0000x reference)
//
#include <hip/hip_runtime.h>
#include <math.h>

// SeesawLoss forward: B=8192 rows, C=4096 classes, P=0.8, Q=2.0, EPS=0.01
// nll_b = M2 + log(sum_j exp(logit_bj - M2)) - o_{b,t}
// logit_bj = o_bj + P*(la_j - la_t)[la_j < la_t] + Q*(ls_j - logclip)[> 0]
// where ls_j = o_j - M - lse1 (log-softmax of detached outputs),
//       logclip = max(ls_t, log(EPS)).
// Row is register-resident (16 floats/thread x 256 threads). NOTE: never take
// the address of the register array (rule #20) — all accesses are via
// explicit .x/.y/.z/.w with compile-time indices.
// Final mean via fixed-point int64 atomic (order-independent -> deterministic).

#define CC 4096
#define SCALE_D 16777216.0   // 2^24 fixed-point scale for the nll sum

__device__ __forceinline__ float wave_max(float v) {
    #pragma unroll
    for (int o = 32; o > 0; o >>= 1) v = fmaxf(v, __shfl_xor(v, o, 64));
    return v;
}
__device__ __forceinline__ float wave_sum(float v) {
    #pragma unroll
    for (int o = 32; o > 0; o >>= 1) v += __shfl_xor(v, o, 64);
    return v;
}

// logit for one element; updates running max. All-register, no memory.
__device__ __forceinline__ float seesaw1(float o, float la, float la_t,
                                         float Koff, float& m2) {
    float mit = (la < la_t) ? 0.8f * (la - la_t) : 0.f;   // mitigation  (<= 0)
    float d   = o - Koff;
    float cmp = (d > 0.f) ? 2.0f * d : 0.f;               // compensation (>= 0)
    float lg  = o + mit + cmp;                            // == o at j==t
    m2 = fmaxf(m2, lg);
    return lg;
}

// One block: bincount via LDS atomics -> clamp -> log table.
// Also zeroes the fixed-point accumulator + completion counter for this call.
__global__ __launch_bounds__(1024) void k_hist(const int* __restrict__ tg, int B,
                                               float* __restrict__ logacc,
                                               unsigned long long* __restrict__ fsum,
                                               unsigned int* __restrict__ counter) {
    __shared__ int hacc[CC];
    const int tid = threadIdx.x;
    #pragma unroll
    for (int k = 0; k < CC / 1024; ++k) hacc[tid + k * 1024] = 0;
    __syncthreads();
    for (int i = tid; i < B; i += 1024) atomicAdd(&hacc[tg[i]], 1);
    __syncthreads();
    #pragma unroll
    for (int k = 0; k < CC / 1024; ++k) {
        int i = tid + k * 1024;
        int a = hacc[i];
        if (a < 1) a = 1;                 // clamp(min=1)
        logacc[i] = __logf((float)a);
    }
    if (tid == 0) { *fsum = 0ULL; *counter = 0u; }
}

__global__ __launch_bounds__(256, 8) void k_row(const float* __restrict__ outp,
                                                const int* __restrict__ tg,
                                                const float* __restrict__ logacc,
                                                unsigned long long* __restrict__ fsum,
                                                unsigned int* __restrict__ counter,
                                                float* __restrict__ out, int B) {
    __shared__ float red_m[4], red_s[4], red_m2[4], red_s2[4];

    const int b   = blockIdx.x;
    const int tid = threadIdx.x;
    const int w   = tid >> 6;
    const bool lane0 = (tid & 63) == 0;

    const float LOG_EPS = -4.605170185988091f;   // log(0.01)

    const float4* __restrict__ src = (const float4*)(outp + (size_t)b * CC);
    const float4* __restrict__ lac = (const float4*)logacc;

    // ---- load row into registers (16 floats/thread), partial max ----
    float4 v0 = src[tid];
    float4 v1 = src[tid + 256];
    float4 v2 = src[tid + 512];
    float4 v3 = src[tid + 768];
    float m = fmaxf(fmaxf(fmaxf(v0.x, v0.y), fmaxf(v0.z, v0.w)),
                    fmaxf(fmaxf(v1.x, v1.y), fmaxf(v1.z, v1.w)));
    m = fmaxf(m, fmaxf(fmaxf(v2.x, v2.y), fmaxf(v2.z, v2.w)));
    m = fmaxf(m, fmaxf(fmaxf(v3.x, v3.y), fmaxf(v3.z, v3.w)));

    const int   t    = tg[b];
    const float o_t  = outp[(size_t)b * CC + t];   // L2-hot (just streamed)
    const float la_t = logacc[t];

    m = wave_max(m);
    if (lane0) red_m[w] = m;
    __syncthreads();
    const float M = fmaxf(fmaxf(red_m[0], red_m[1]), fmaxf(red_m[2], red_m[3]));

    // ---- sum exp(o - M) from registers ----
    float s = 0.f;
    s += __expf(v0.x - M); s += __expf(v0.y - M);
    s += __expf(v0.z - M); s += __expf(v0.w - M);
    s += __expf(v1.x - M); s += __expf(v1.y - M);
    s += __expf(v1.z - M); s += __expf(v1.w - M);
    s += __expf(v2.x - M); s += __expf(v2.y - M);
    s += __expf(v2.z - M); s += __expf(v2.w - M);
    s += __expf(v3.x - M); s += __expf(v3.y - M);
    s += __expf(v3.z - M); s += __expf(v3.w - M);
    s = wave_sum(s);
    if (lane0) red_s[w] = s;
    __syncthreads();
    const float S    = (red_s[0] + red_s[1]) + (red_s[2] + red_s[3]);
    const float lse1 = __logf(S);

    const float ls_t    = o_t - M - lse1;
    const float logclip = fmaxf(ls_t, LOG_EPS);
    const float Koff    = M + lse1 + logclip;      // d_j = o_j - Koff

    // ---- logits in place, partial max (explicit components, no addressing) ----
    float m2 = -1e30f;
    {
        float4 la = lac[tid];
        v0.x = seesaw1(v0.x, la.x, la_t, Koff, m2);
        v0.y = seesaw1(v0.y, la.y, la_t, Koff, m2);
        v0.z = seesaw1(v0.z, la.z, la_t, Koff, m2);
        v0.w = seesaw1(v0.w, la.w, la_t, Koff, m2);
    }
    {
        float4 la = lac[tid + 256];
        v1.x = seesaw1(v1.x, la.x, la_t, Koff, m2);
        v1.y = seesaw1(v1.y, la.y, la_t, Koff, m2);
        v1.z = seesaw1(v1.z, la.z, la_t, Koff, m2);
        v1.w = seesaw1(v1.w, la.w, la_t, Koff, m2);
    }
    {
        float4 la = lac[tid + 512];
        v2.x = seesaw1(v2.x, la.x, la_t, Koff, m2);
        v2.y = seesaw1(v2.y, la.y, la_t, Koff, m2);
        v2.z = seesaw1(v2.z, la.z, la_t, Koff, m2);
        v2.w = seesaw1(v2.w, la.w, la_t, Koff, m2);
    }
    {
        float4 la = lac[tid + 768];
        v3.x = seesaw1(v3.x, la.x, la_t, Koff, m2);
        v3.y = seesaw1(v3.y, la.y, la_t, Koff, m2);
        v3.z = seesaw1(v3.z, la.z, la_t, Koff, m2);
        v3.w = seesaw1(v3.w, la.w, la_t, Koff, m2);
    }
    m2 = wave_max(m2);
    if (lane0) red_m2[w] = m2;
    __syncthreads();
    const float M2 = fmaxf(fmaxf(red_m2[0], red_m2[1]), fmaxf(red_m2[2], red_m2[3]));

    // ---- sum exp(logit - M2) ----
    float s2 = 0.f;
    s2 += __expf(v0.x - M2); s2 += __expf(v0.y - M2);
    s2 += __expf(v0.z - M2); s2 += __expf(v0.w - M2);
    s2 += __expf(v1.x - M2); s2 += __expf(v1.y - M2);
    s2 += __expf(v1.z - M2); s2 += __expf(v1.w - M2);
    s2 += __expf(v2.x - M2); s2 += __expf(v2.y - M2);
    s2 += __expf(v2.z - M2); s2 += __expf(v2.w - M2);
    s2 += __expf(v3.x - M2); s2 += __expf(v3.y - M2);
    s2 += __expf(v3.z - M2); s2 += __expf(v3.w - M2);
    s2 = wave_sum(s2);
    if (lane0) red_s2[w] = s2;
    __syncthreads();

    if (tid == 0) {
        float S2   = (red_s2[0] + red_s2[1]) + (red_s2[2] + red_s2[3]);
        float nllv = M2 + __logf(S2) - o_t;        // >= 0
        long long q = (long long)((double)nllv * SCALE_D + 0.5);
        atomicAdd(fsum, (unsigned long long)q);
        __threadfence();
        unsigned int done = atomicAdd(counter, 1u);
        if (done == (unsigned int)(gridDim.x - 1)) {
            unsigned long long total = atomicAdd(fsum, 0ULL);  // device-scope read
            out[0] = (float)((double)(long long)total / SCALE_D / (double)B);
        }
    }
}

extern "C" void kernel_launch(void* const* d_in, const int* in_sizes, int n_in,
                              void* d_out, int out_size, void* d_ws, size_t ws_size,
                              hipStream_t stream) {
    const float* outp = (const float*)d_in[0];   // [B, C] f32
    const int*   tg   = (const int*)d_in[1];     // [B] i32
    float*       out  = (float*)d_out;           // scalar f32

    const int B = in_sizes[1];                   // 8192 (C fixed at 4096)

    char* ws = (char*)d_ws;
    unsigned long long* fsum    = (unsigned long long*)ws;        // 8 B
    unsigned int*       counter = (unsigned int*)(ws + 8);        // 4 B
    float*              logacc  = (float*)(ws + 64);              // 16 KB

    k_hist<<<1, 1024, 0, stream>>>(tg, B, logacc, fsum, counter);
    k_row <<<B, 256, 0, stream>>>(outp, tg, logacc, fsum, counter, out, B);
}

// Round 6
// 43.862 us; speedup vs baseline: 15.3396x; 15.3396x over previous
//
#include <hip/hip_runtime.h>
#include <math.h>

// SeesawLoss forward: B=8192 rows, C=4096 classes, P=0.8, Q=2.0, EPS=0.01
// nll_b = M2 + log(sum_j exp(logit_bj - M2)) - o_{b,t}
// logit_bj = o_bj + P*(la_j - la_t)[la_j < la_t] + Q*(ls_j - logclip)[> 0]
// where ls_j = o_j - M - lse1 (log-softmax of detached outputs),
//       logclip = max(ls_t, log(EPS)).
// Row is register-resident (16 floats/thread x 256 threads), explicit
// .x/.y/.z/.w accesses only (rule #20: never take the address of the array).
// Finalize: plain per-row store + 1-block deterministic reduce. NO global
// atomics / __threadfence in k_row — the R4/R5 same-address atomic +
// agent-scope fence from 8192 blocks serialized the whole kernel (~670us).

#define CC 4096

__device__ __forceinline__ float wave_max(float v) {
    #pragma unroll
    for (int o = 32; o > 0; o >>= 1) v = fmaxf(v, __shfl_xor(v, o, 64));
    return v;
}
__device__ __forceinline__ float wave_sum(float v) {
    #pragma unroll
    for (int o = 32; o > 0; o >>= 1) v += __shfl_xor(v, o, 64);
    return v;
}

// logit for one element; updates running max. All-register, no memory.
__device__ __forceinline__ float seesaw1(float o, float la, float la_t,
                                         float Koff, float& m2) {
    float mit = (la < la_t) ? 0.8f * (la - la_t) : 0.f;   // mitigation  (<= 0)
    float d   = o - Koff;
    float cmp = (d > 0.f) ? 2.0f * d : 0.f;               // compensation (>= 0)
    float lg  = o + mit + cmp;                            // == o at j==t
    m2 = fmaxf(m2, lg);
    return lg;
}

// One block: bincount via LDS atomics -> clamp -> log table.
__global__ __launch_bounds__(1024) void k_hist(const int* __restrict__ tg, int B,
                                               float* __restrict__ logacc) {
    __shared__ int hacc[CC];
    const int tid = threadIdx.x;
    #pragma unroll
    for (int k = 0; k < CC / 1024; ++k) hacc[tid + k * 1024] = 0;
    __syncthreads();
    for (int i = tid; i < B; i += 1024) atomicAdd(&hacc[tg[i]], 1);
    __syncthreads();
    #pragma unroll
    for (int k = 0; k < CC / 1024; ++k) {
        int i = tid + k * 1024;
        int a = hacc[i];
        if (a < 1) a = 1;                 // clamp(min=1)
        logacc[i] = __logf((float)a);
    }
}

__global__ __launch_bounds__(256, 8) void k_row(const float* __restrict__ outp,
                                                const int* __restrict__ tg,
                                                const float* __restrict__ logacc,
                                                float* __restrict__ nll) {
    __shared__ float red_m[4], red_s[4], red_m2[4], red_s2[4];

    const int b   = blockIdx.x;
    const int tid = threadIdx.x;
    const int w   = tid >> 6;
    const bool lane0 = (tid & 63) == 0;

    const float LOG_EPS = -4.605170185988091f;   // log(0.01)

    const float4* __restrict__ src = (const float4*)(outp + (size_t)b * CC);
    const float4* __restrict__ lac = (const float4*)logacc;

    // ---- load row into registers (16 floats/thread), partial max ----
    float4 v0 = src[tid];
    float4 v1 = src[tid + 256];
    float4 v2 = src[tid + 512];
    float4 v3 = src[tid + 768];
    float m = fmaxf(fmaxf(fmaxf(v0.x, v0.y), fmaxf(v0.z, v0.w)),
                    fmaxf(fmaxf(v1.x, v1.y), fmaxf(v1.z, v1.w)));
    m = fmaxf(m, fmaxf(fmaxf(v2.x, v2.y), fmaxf(v2.z, v2.w)));
    m = fmaxf(m, fmaxf(fmaxf(v3.x, v3.y), fmaxf(v3.z, v3.w)));

    const int   t    = tg[b];
    const float o_t  = outp[(size_t)b * CC + t];   // L1/L2-hot (just streamed)
    const float la_t = logacc[t];

    m = wave_max(m);
    if (lane0) red_m[w] = m;
    __syncthreads();
    const float M = fmaxf(fmaxf(red_m[0], red_m[1]), fmaxf(red_m[2], red_m[3]));

    // ---- sum exp(o - M) from registers ----
    float s = 0.f;
    s += __expf(v0.x - M); s += __expf(v0.y - M);
    s += __expf(v0.z - M); s += __expf(v0.w - M);
    s += __expf(v1.x - M); s += __expf(v1.y - M);
    s += __expf(v1.z - M); s += __expf(v1.w - M);
    s += __expf(v2.x - M); s += __expf(v2.y - M);
    s += __expf(v2.z - M); s += __expf(v2.w - M);
    s += __expf(v3.x - M); s += __expf(v3.y - M);
    s += __expf(v3.z - M); s += __expf(v3.w - M);
    s = wave_sum(s);
    if (lane0) red_s[w] = s;
    __syncthreads();
    const float S    = (red_s[0] + red_s[1]) + (red_s[2] + red_s[3]);
    const float lse1 = __logf(S);

    const float ls_t    = o_t - M - lse1;
    const float logclip = fmaxf(ls_t, LOG_EPS);
    const float Koff    = M + lse1 + logclip;      // d_j = o_j - Koff

    // ---- logits in place, partial max (explicit components, no addressing) ----
    float m2 = -1e30f;
    {
        float4 la = lac[tid];
        v0.x = seesaw1(v0.x, la.x, la_t, Koff, m2);
        v0.y = seesaw1(v0.y, la.y, la_t, Koff, m2);
        v0.z = seesaw1(v0.z, la.z, la_t, Koff, m2);
        v0.w = seesaw1(v0.w, la.w, la_t, Koff, m2);
    }
    {
        float4 la = lac[tid + 256];
        v1.x = seesaw1(v1.x, la.x, la_t, Koff, m2);
        v1.y = seesaw1(v1.y, la.y, la_t, Koff, m2);
        v1.z = seesaw1(v1.z, la.z, la_t, Koff, m2);
        v1.w = seesaw1(v1.w, la.w, la_t, Koff, m2);
    }
    {
        float4 la = lac[tid + 512];
        v2.x = seesaw1(v2.x, la.x, la_t, Koff, m2);
        v2.y = seesaw1(v2.y, la.y, la_t, Koff, m2);
        v2.z = seesaw1(v2.z, la.z, la_t, Koff, m2);
        v2.w = seesaw1(v2.w, la.w, la_t, Koff, m2);
    }
    {
        float4 la = lac[tid + 768];
        v3.x = seesaw1(v3.x, la.x, la_t, Koff, m2);
        v3.y = seesaw1(v3.y, la.y, la_t, Koff, m2);
        v3.z = seesaw1(v3.z, la.z, la_t, Koff, m2);
        v3.w = seesaw1(v3.w, la.w, la_t, Koff, m2);
    }
    m2 = wave_max(m2);
    if (lane0) red_m2[w] = m2;
    __syncthreads();
    const float M2 = fmaxf(fmaxf(red_m2[0], red_m2[1]), fmaxf(red_m2[2], red_m2[3]));

    // ---- sum exp(logit - M2) ----
    float s2 = 0.f;
    s2 += __expf(v0.x - M2); s2 += __expf(v0.y - M2);
    s2 += __expf(v0.z - M2); s2 += __expf(v0.w - M2);
    s2 += __expf(v1.x - M2); s2 += __expf(v1.y - M2);
    s2 += __expf(v1.z - M2); s2 += __expf(v1.w - M2);
    s2 += __expf(v2.x - M2); s2 += __expf(v2.y - M2);
    s2 += __expf(v2.z - M2); s2 += __expf(v2.w - M2);
    s2 += __expf(v3.x - M2); s2 += __expf(v3.y - M2);
    s2 += __expf(v3.z - M2); s2 += __expf(v3.w - M2);
    s2 = wave_sum(s2);
    if (lane0) red_s2[w] = s2;
    __syncthreads();

    if (tid == 0) {
        float S2 = (red_s2[0] + red_s2[1]) + (red_s2[2] + red_s2[3]);
        nll[b] = M2 + __logf(S2) - o_t;            // plain store, no atomics
    }
}

// deterministic final mean: fixed strided partials + fixed tree
__global__ __launch_bounds__(256) void k_reduce(const float* __restrict__ nll,
                                                float* __restrict__ out, int B) {
    __shared__ float red[4];
    const int tid = threadIdx.x;
    float s = 0.f;
    for (int i = tid; i < B; i += 256) s += nll[i];
    s = wave_sum(s);
    if ((tid & 63) == 0) red[tid >> 6] = s;
    __syncthreads();
    if (tid == 0) out[0] = ((red[0] + red[1]) + (red[2] + red[3])) / (float)B;
}

extern "C" void kernel_launch(void* const* d_in, const int* in_sizes, int n_in,
                              void* d_out, int out_size, void* d_ws, size_t ws_size,
                              hipStream_t stream) {
    const float* outp = (const float*)d_in[0];   // [B, C] f32
    const int*   tg   = (const int*)d_in[1];     // [B] i32
    float*       out  = (float*)d_out;           // scalar f32

    const int B = in_sizes[1];                   // 8192 (C fixed at 4096)

    char*  ws     = (char*)d_ws;
    float* logacc = (float*)ws;                  // 16 KB
    float* nll    = (float*)(ws + 16384);        // B*4 = 32 KB

    k_hist  <<<1, 1024, 0, stream>>>(tg, B, logacc);
    k_row   <<<B, 256, 0, stream>>>(outp, tg, logacc, nll);
    k_reduce<<<1, 256, 0, stream>>>(nll, out, B);
}

// Round 7
// 37.394 us; speedup vs baseline: 17.9927x; 1.1730x over previous
//
#include <hip/hip_runtime.h>
#include <math.h>

// SeesawLoss forward: B=8192 rows, C=4096 classes, P=0.8, Q=2.0, EPS=0.01
// nll_b = M2' + log(sum_j exp(logit_bj - M2')) - o_{b,t}
// logit_bj = o_bj + P*(la_j - la_t)[la_j < la_t] + Q*(o_j - Koff)[> 0]
// Koff = M + lse1 + logclip;  logclip = max(o_t - M - lse1, log(EPS)).
// M2' = M + max(0, Q*(M-Koff)) is an analytic upper bound on all logits
// (mitigation <= 0, compensation <= Q*max(0, M-Koff)), within ~12 of the
// true max -> numerically safe stabilizer, saves the 3rd reduction pass.
// Row is register-resident (16 floats/thread x 256 threads), explicit
// .x/.y/.z/.w accesses only (rule #20). Plain per-row store + 1-block
// deterministic reduce (NO grid-wide atomics: R4/R5 showed same-address
// device atomics + fence from 8192 blocks serialize to ~670us on 8 XCDs).

#define CC 4096

__device__ __forceinline__ float wave_max(float v) {
    #pragma unroll
    for (int o = 32; o > 0; o >>= 1) v = fmaxf(v, __shfl_xor(v, o, 64));
    return v;
}
__device__ __forceinline__ float wave_sum(float v) {
    #pragma unroll
    for (int o = 32; o > 0; o >>= 1) v += __shfl_xor(v, o, 64);
    return v;
}

// exp-sum of one float4 against stabilizer M (3-add tree, independent of
// other accumulators -> 4-way ILP across v0..v3)
__device__ __forceinline__ float esum4(float4 v, float M) {
    return (__expf(v.x - M) + __expf(v.y - M)) +
           (__expf(v.z - M) + __expf(v.w - M));
}

// logit for one element (all-register)
__device__ __forceinline__ float seesaw1(float o, float la, float la_t,
                                         float Koff) {
    float mit = (la < la_t) ? 0.8f * (la - la_t) : 0.f;   // mitigation  (<= 0)
    float d   = o - Koff;
    float cmp = (d > 0.f) ? 2.0f * d : 0.f;               // compensation (>= 0)
    return o + mit + cmp;                                 // == o at j==t
}

// fused logit + exp-sum for one float4 group
__device__ __forceinline__ float lsum4(float4 v, float4 la, float la_t,
                                       float Koff, float M2) {
    float a = __expf(seesaw1(v.x, la.x, la_t, Koff) - M2);
    float b = __expf(seesaw1(v.y, la.y, la_t, Koff) - M2);
    float c = __expf(seesaw1(v.z, la.z, la_t, Koff) - M2);
    float d = __expf(seesaw1(v.w, la.w, la_t, Koff) - M2);
    return (a + b) + (c + d);
}

// One block: bincount via LDS atomics -> clamp -> log table.
__global__ __launch_bounds__(1024) void k_hist(const int* __restrict__ tg, int B,
                                               float* __restrict__ logacc) {
    __shared__ int hacc[CC];
    const int tid = threadIdx.x;
    #pragma unroll
    for (int k = 0; k < CC / 1024; ++k) hacc[tid + k * 1024] = 0;
    __syncthreads();
    for (int i = tid; i < B; i += 1024) atomicAdd(&hacc[tg[i]], 1);
    __syncthreads();
    #pragma unroll
    for (int k = 0; k < CC / 1024; ++k) {
        int i = tid + k * 1024;
        int a = hacc[i];
        if (a < 1) a = 1;                 // clamp(min=1)
        logacc[i] = __logf((float)a);
    }
}

__global__ __launch_bounds__(256, 8) void k_row(const float* __restrict__ outp,
                                                const int* __restrict__ tg,
                                                const float* __restrict__ logacc,
                                                float* __restrict__ nll) {
    __shared__ float red_m[4], red_s[4], red_s2[4];

    const int b   = blockIdx.x;
    const int tid = threadIdx.x;
    const int w   = tid >> 6;
    const bool lane0 = (tid & 63) == 0;

    const float LOG_EPS = -4.605170185988091f;   // log(0.01)

    const float4* __restrict__ src = (const float4*)(outp + (size_t)b * CC);
    const float4* __restrict__ lac = (const float4*)logacc;

    // ---- load row into registers (16 floats/thread), tree max ----
    float4 v0 = src[tid];
    float4 v1 = src[tid + 256];
    float4 v2 = src[tid + 512];
    float4 v3 = src[tid + 768];
    float m0 = fmaxf(fmaxf(v0.x, v0.y), fmaxf(v0.z, v0.w));
    float m1 = fmaxf(fmaxf(v1.x, v1.y), fmaxf(v1.z, v1.w));
    float m2 = fmaxf(fmaxf(v2.x, v2.y), fmaxf(v2.z, v2.w));
    float m3 = fmaxf(fmaxf(v3.x, v3.y), fmaxf(v3.z, v3.w));
    float m  = fmaxf(fmaxf(m0, m1), fmaxf(m2, m3));

    const int   t    = tg[b];
    const float o_t  = outp[(size_t)b * CC + t];   // L1/L2-hot (just streamed)
    const float la_t = logacc[t];

    m = wave_max(m);
    if (lane0) red_m[w] = m;
    __syncthreads();
    const float M = fmaxf(fmaxf(red_m[0], red_m[1]), fmaxf(red_m[2], red_m[3]));

    // ---- sum exp(o - M): 4 independent accumulators (ILP) ----
    float s0 = esum4(v0, M);
    float s1 = esum4(v1, M);
    float s2 = esum4(v2, M);
    float s3 = esum4(v3, M);
    float s  = wave_sum((s0 + s1) + (s2 + s3));
    if (lane0) red_s[w] = s;
    __syncthreads();
    const float S    = (red_s[0] + red_s[1]) + (red_s[2] + red_s[3]);
    const float lse1 = __logf(S);

    const float ls_t    = o_t - M - lse1;
    const float logclip = fmaxf(ls_t, LOG_EPS);
    const float Koff    = M + lse1 + logclip;              // d_j = o_j - Koff
    const float M2      = M + fmaxf(0.f, 2.0f * (M - Koff)); // analytic bound

    // ---- fused logit + sum exp(logit - M2): 4 accumulators ----
    float z0 = lsum4(v0, lac[tid      ], la_t, Koff, M2);
    float z1 = lsum4(v1, lac[tid + 256], la_t, Koff, M2);
    float z2 = lsum4(v2, lac[tid + 512], la_t, Koff, M2);
    float z3 = lsum4(v3, lac[tid + 768], la_t, Koff, M2);
    float z  = wave_sum((z0 + z1) + (z2 + z3));
    if (lane0) red_s2[w] = z;
    __syncthreads();

    if (tid == 0) {
        float S2 = (red_s2[0] + red_s2[1]) + (red_s2[2] + red_s2[3]);
        nll[b] = M2 + __logf(S2) - o_t;            // plain store, no atomics
    }
}

// deterministic final mean: fixed strided partials + fixed tree
__global__ __launch_bounds__(1024) void k_reduce(const float* __restrict__ nll,
                                                 float* __restrict__ out, int B) {
    __shared__ float red[16];
    const int tid = threadIdx.x;
    float s = 0.f;
    for (int i = tid; i < B; i += 1024) s += nll[i];
    s = wave_sum(s);
    if ((tid & 63) == 0) red[tid >> 6] = s;
    __syncthreads();
    if (tid == 0) {
        float tsum = 0.f;
        #pragma unroll
        for (int k = 0; k < 16; ++k) tsum += red[k];
        out[0] = tsum / (float)B;
    }
}

extern "C" void kernel_launch(void* const* d_in, const int* in_sizes, int n_in,
                              void* d_out, int out_size, void* d_ws, size_t ws_size,
                              hipStream_t stream) {
    const float* outp = (const float*)d_in[0];   // [B, C] f32
    const int*   tg   = (const int*)d_in[1];     // [B] i32
    float*       out  = (float*)d_out;           // scalar f32

    const int B = in_sizes[1];                   // 8192 (C fixed at 4096)

    char*  ws     = (char*)d_ws;
    float* logacc = (float*)ws;                  // 16 KB
    float* nll    = (float*)(ws + 16384);        // B*4 = 32 KB

    k_hist  <<<1, 1024, 0, stream>>>(tg, B, logacc);
    k_row   <<<B, 256, 0, stream>>>(outp, tg, logacc, nll);
    k_reduce<<<1, 1024, 0, stream>>>(nll, out, B);
}